// Round 4
// 145.469 us; speedup vs baseline: 1.0047x; 1.0047x over previous
//
#include <hip/hip_runtime.h>
#include <cmath>

// Problem constants
constexpr int B_  = 2;
constexpr int T_  = 512;
constexpr int DM_ = 1024;
constexpr int H_  = 16;
constexpr int DH_ = 64;
constexpr int D_  = 32;
constexpr int R_  = 4;
constexpr int BH_ = B_ * H_;   // 32

typedef __bf16 bf16x8 __attribute__((ext_vector_type(8)));
typedef float  f32x4  __attribute__((ext_vector_type(4)));
typedef unsigned short u16x8 __attribute__((ext_vector_type(8)));

__device__ __forceinline__ unsigned short f2bf(float f) {
    unsigned u = __float_as_uint(f);
    return (unsigned short)((u + 0x7fffu + ((u >> 16) & 1u)) >> 16);  // RNE
}
__device__ __forceinline__ float bf2f(unsigned short v) {
    return __uint_as_float((unsigned)v << 16);
}
__device__ __forceinline__ void gload16(const void* g, void* l) {
    __builtin_amdgcn_global_load_lds(
        (const __attribute__((address_space(1))) void*)g,
        (__attribute__((address_space(3))) void*)l, 16, 0, 0);
}

// -------------------------------------------------------------------------
// Prep: z=0..3 -> transpose+convert Wq/Wk/Wv/Wo to (N x K) bf16;
//       z=4    -> convert x to bf16 row-major.  (unchanged)
// -------------------------------------------------------------------------
__global__ __launch_bounds__(256) void prep_kernel(
    const float* __restrict__ x,
    const float* __restrict__ Wq, const float* __restrict__ Wk,
    const float* __restrict__ Wv, const float* __restrict__ Wo,
    unsigned short* __restrict__ xb,
    unsigned short* __restrict__ wqb, unsigned short* __restrict__ wkb,
    unsigned short* __restrict__ wvb, unsigned short* __restrict__ wob)
{
    const int t = threadIdx.x;
    const int z = blockIdx.z;
    if (z == 4) {
        int base = (blockIdx.y * 16 + blockIdx.x) * 4096 + t * 16;
#pragma unroll
        for (int c = 0; c < 4; ++c) {
            float4 v = *(const float4*)&x[base + c * 4];
            ushort4 o = { f2bf(v.x), f2bf(v.y), f2bf(v.z), f2bf(v.w) };
            *(ushort4*)&xb[base + c * 4] = o;
        }
        return;
    }
    __shared__ __align__(16) unsigned short Ls[64][72];
    const float* W = (z == 0) ? Wq : (z == 1) ? Wk : (z == 2) ? Wv : Wo;
    unsigned short* O = (z == 0) ? wqb : (z == 1) ? wkb : (z == 2) ? wvb : wob;
    const int k0 = blockIdx.x * 64;
    const int n0 = blockIdx.y * 64;
#pragma unroll
    for (int it = 0; it < 4; ++it) {
        int r = it * 16 + (t >> 4);
        int c = (t & 15) * 4;
        float4 v4 = *(const float4*)&W[(size_t)(k0 + r) * DM_ + n0 + c];
        Ls[c + 0][r] = f2bf(v4.x); Ls[c + 1][r] = f2bf(v4.y);
        Ls[c + 2][r] = f2bf(v4.z); Ls[c + 3][r] = f2bf(v4.w);
    }
    __syncthreads();
#pragma unroll
    for (int it = 0; it < 2; ++it) {
        int nl = it * 32 + (t >> 3);
        int kc = (t & 7) * 8;
        *(u16x8*)&O[(size_t)(n0 + nl) * DM_ + k0 + kc] = *(const u16x8*)&Ls[nl][kc];
    }
}

// -------------------------------------------------------------------------
// 64x64-tile bf16 MFMA GEMM, BK=64 swizzled, DOUBLE-BUFFERED LDS.
// (unchanged)
// -------------------------------------------------------------------------
template <int EPI>
__global__ __launch_bounds__(256) void mfma_gemm_db(
    const unsigned short* __restrict__ A,
    const unsigned short* __restrict__ Bt0,
    const unsigned short* __restrict__ Bt1,
    const unsigned short* __restrict__ Bt2,
    float* __restrict__ C0, float* __restrict__ C1,
    unsigned short* __restrict__ vT)
{
    __shared__ __align__(16) unsigned short As[2][64 * 64];   // 16 KB x2
    __shared__ __align__(16) unsigned short Bs[2][64 * 64];   // total 32 KB
    const int tid  = threadIdx.x;
    const int lane = tid & 63;
    const int w    = tid >> 6;
    const int wm   = (w & 1) * 32;
    const int wn   = (w >> 1) * 32;
    const int l15  = lane & 15, quad = lane >> 4;

    const int bm = blockIdx.y * 64;
    int bn, which = 0;
    const unsigned short* Bt;
    if (EPI == 0) {
        int n0 = blockIdx.x * 64;
        which = n0 >> 10;
        bn = n0 & 1023;
        Bt = (which == 0) ? Bt0 : (which == 1) ? Bt1 : Bt2;
    } else {
        bn = blockIdx.x * 64;
        Bt = Bt0;
    }

    const int srow = tid >> 3, kcs = tid & 7, kcg = kcs ^ (srow & 7);
    const unsigned short* Ap0 = A  + (size_t)(bm + srow) * DM_ + kcg * 8;
    const unsigned short* Bp0 = Bt + (size_t)(bn + srow) * DM_ + kcg * 8;
    const unsigned short* Ap1 = Ap0 + 32 * DM_;
    const unsigned short* Bp1 = Bp0 + 32 * DM_;

    // prologue: tile 0 into buffer 0
    gload16(Ap0, &As[0][tid * 8]);
    gload16(Ap1, &As[0][tid * 8 + 2048]);
    gload16(Bp0, &Bs[0][tid * 8]);
    gload16(Bp1, &Bs[0][tid * 8 + 2048]);

    f32x4 acc[2][2] = {};
#pragma unroll
    for (int k = 0; k < 16; ++k) {
        const int cur = k & 1, nxt = cur ^ 1;
        // barrier1: all waves done reading buf[nxt] (iter k-1's frags)
        __builtin_amdgcn_s_barrier();
        if (k + 1 < 16) {
            const int off = (k + 1) * 64;
            gload16(Ap0 + off, &As[nxt][tid * 8]);
            gload16(Ap1 + off, &As[nxt][tid * 8 + 2048]);
            gload16(Bp0 + off, &Bs[nxt][tid * 8]);
            gload16(Bp1 + off, &Bs[nxt][tid * 8 + 2048]);
            __builtin_amdgcn_s_waitcnt(0x0F74);   // vmcnt(4): cur tile done
        } else {
            __builtin_amdgcn_s_waitcnt(0x0F70);   // vmcnt(0): last tile
        }
        // barrier2: everyone's cur-tile loads complete & visible
        __builtin_amdgcn_s_barrier();

        bf16x8 af[2][2], bfr[2][2];
#pragma unroll
        for (int ki = 0; ki < 2; ++ki)
#pragma unroll
            for (int i = 0; i < 2; ++i) {
                int ra = wm + i * 16 + l15;
                int rb = wn + i * 16 + l15;
                int kch = ki * 4 + quad;
                af[ki][i]  = *(const bf16x8*)&As[cur][ra * 64 + (kch ^ (ra & 7)) * 8];
                bfr[ki][i] = *(const bf16x8*)&Bs[cur][rb * 64 + (kch ^ (rb & 7)) * 8];
            }
#pragma unroll
        for (int mi = 0; mi < 2; ++mi)
#pragma unroll
            for (int ni = 0; ni < 2; ++ni) {
                acc[mi][ni] = __builtin_amdgcn_mfma_f32_16x16x32_bf16(
                    af[0][mi], bfr[0][ni], acc[mi][ni], 0, 0, 0);
                acc[mi][ni] = __builtin_amdgcn_mfma_f32_16x16x32_bf16(
                    af[1][mi], bfr[1][ni], acc[mi][ni], 0, 0, 0);
            }
    }

#pragma unroll
    for (int mi = 0; mi < 2; ++mi)
#pragma unroll
        for (int ni = 0; ni < 2; ++ni) {
            f32x4 a = acc[mi][ni];
            int col = wn + ni * 16 + l15;
#pragma unroll
            for (int r = 0; r < 4; ++r) {
                int row = bm + wm + mi * 16 + quad * 4 + r;
                if (EPI == 0) {
                    int h = bn >> 6, d = col;       // 64-wide tile == one head
                    int bb = row >> 9, tt = row & (T_ - 1);
                    if (which == 2) {
                        vT[(((size_t)bb * H_ + h) * DH_ + d) * T_ + tt] = f2bf(a[r]);
                    } else {
                        float* C = (which == 0) ? C0 : C1;
                        C[(((size_t)bb * H_ + h) * T_ + tt) * DH_ + d] = a[r];
                    }
                } else {
                    C0[(size_t)row * DM_ + bn + col] = a[r];
                }
            }
        }
}

// -------------------------------------------------------------------------
// Per-row features — full-wave matvecs, shfl reductions, no __syncthreads
// (all LDS wave-private: indexed [w]; same-wave DS ops are in-order).
// -------------------------------------------------------------------------
__global__ __launch_bounds__(256) void feat_both(
    const float* __restrict__ q_raw, const float* __restrict__ k_raw,
    const float* __restrict__ Wqm,   const float* __restrict__ Wkm,
    const float* __restrict__ Wmetric,
    unsigned short* __restrict__ a_hi, unsigned short* __restrict__ a_lo,
    unsigned short* __restrict__ km_hi, unsigned short* __restrict__ km_lo,
    float* __restrict__ q2p, float* __restrict__ k2,
    unsigned short* __restrict__ Urb)
{
    const bool QSIDE = (blockIdx.y == 0);
    const float* raw = QSIDE ? q_raw : k_raw;
    const float* Wm  = QSIDE ? Wqm   : Wkm;

    __shared__ float qrs[4][64];
    __shared__ float qms[4][32];
    const int tid  = threadIdx.x;
    const int w    = tid >> 6;
    const int lane = tid & 63;
    const int row  = blockIdx.x * 4 + w;       // bh*T + t
    const int t    = row & (T_ - 1);
    const int bh   = row >> 9;

    const int m  = lane & 31;    // output index / rope freq index
    const int hh = lane >> 5;    // d-half for the qm matvec

    // --- RoPE (unchanged math) ---
    float rv = raw[(size_t)row * 64 + lane];
    float ang = (float)t * expf((float)m * -0.28782313662425575f);
    float s, c;
    sincosf(ang, &s, &c);
    float partner = __shfl_xor(rv, 32);
    float qr = (lane < 32) ? (rv * c - partner * s) : (partner * s + rv * c);
    qrs[w][lane] = qr;

    // --- qm = sigmoid(q_rope @ Wm): full-wave, d split across halves ---
    float acc = 0.f;
#pragma unroll 8
    for (int i = 0; i < 32; ++i) {
        int d = hh * 32 + i;
        acc += qrs[w][d] * Wm[d * 32 + m];
    }
    acc += __shfl_xor(acc, 32);
    const float qm = 1.0f / (1.0f + __expf(-acc));   // all 64 lanes: qm[m]
    if (hh == 0) qms[w][m] = qm;

    if (!QSIDE) {
        if (lane < 32) {
            unsigned short hi = f2bf(qm);
            unsigned short lo = f2bf(qm - bf2f(hi));
            size_t off = (size_t)row * 32 + lane;
            km_hi[off] = hi; km_lo[off] = lo;
        }
        float sq = (lane < 32) ? qm * qm : 0.f;
        sq += __shfl_xor(sq, 32); sq += __shfl_xor(sq, 16);
        sq += __shfl_xor(sq, 8);  sq += __shfl_xor(sq, 4);
        sq += __shfl_xor(sq, 2);  sq += __shfl_xor(sq, 1);
        if (lane == 0) k2[row] = sq;
        return;
    }

    // --- Us = qm @ Wmetric (128 outputs; lane owns n = 2*lane, 2*lane+1) ---
    float a0 = 0.f, a1 = 0.f;
#pragma unroll 8
    for (int mm = 0; mm < 32; ++mm) {
        float qv = qms[w][mm];
        float2 wv = *(const float2*)&Wmetric[mm * 128 + lane * 2];
        a0 += qv * wv.x;
        a1 += qv * wv.y;
    }

    // Urb write: Us index n -> (d = n>>2, r = n&3)
    {
        int n0i = lane * 2;
        int r0 = n0i & 3, d0 = n0i >> 2;
        Urb[(((size_t)bh * R_ + r0    ) * T_ + t) * D_ + d0] = f2bf(a0);
        Urb[(((size_t)bh * R_ + r0 + 1) * T_ + t) * D_ + d0] = f2bf(a1);
    }

    // --- Uq[r] = sum_d Us[d*4+r] * qm[d] ---
    float dq = qms[w][lane >> 1];
    float u0 = a0 * dq, u1 = a1 * dq;
    u0 += __shfl_xor(u0, 2);  u1 += __shfl_xor(u1, 2);
    u0 += __shfl_xor(u0, 4);  u1 += __shfl_xor(u1, 4);
    u0 += __shfl_xor(u0, 8);  u1 += __shfl_xor(u1, 8);
    u0 += __shfl_xor(u0, 16); u1 += __shfl_xor(u1, 16);
    u0 += __shfl_xor(u0, 32); u1 += __shfl_xor(u1, 32);
    float v0 = __shfl_xor(u0, 1), v1 = __shfl_xor(u1, 1);
    const bool odd = (lane & 1);
    float Uq0 = odd ? v0 : u0;
    float Uq1 = odd ? v1 : u1;
    float Uq2 = odd ? u0 : v0;
    float Uq3 = odd ? u1 : v1;

    // --- a = qm + sum_r Uq[r]*Us[m*4+r]  (gather Us[4m..4m+3] via shfl) ---
    {
        int src = m * 2;                         // lane holding n=4m,4m+1
        float s0 = __shfl(a0, src);
        float s1 = __shfl(a1, src);
        float s2 = __shfl(a0, src + 1);
        float s3 = __shfl(a1, src + 1);
        if (lane < 32) {
            float b = Uq0 * s0 + Uq1 * s1 + Uq2 * s2 + Uq3 * s3;
            float a = qm + b;
            unsigned short hi = f2bf(a);
            unsigned short lo = f2bf(a - bf2f(hi));
            size_t off = (size_t)row * 32 + lane;
            a_hi[off] = hi; a_lo[off] = lo;
        }
    }

    // --- q2 = sum_m qm^2 + sum_r Uq[r]^2 ---
    float sq = (lane < 32) ? qm * qm : 0.f;
    sq += __shfl_xor(sq, 32); sq += __shfl_xor(sq, 16);
    sq += __shfl_xor(sq, 8);  sq += __shfl_xor(sq, 4);
    sq += __shfl_xor(sq, 2);  sq += __shfl_xor(sq, 1);
    if (lane == 0)
        q2p[row] = sq + Uq0 * Uq0 + Uq1 * Uq1 + Uq2 * Uq2 + Uq3 * Uq3;
}

// -------------------------------------------------------------------------
// MFMA attention (unchanged).
// -------------------------------------------------------------------------
constexpr int PROW = 40;
__global__ __launch_bounds__(256) void attn_mfma(
    const unsigned short* __restrict__ a_hi, const unsigned short* __restrict__ a_lo,
    const unsigned short* __restrict__ km_hi, const unsigned short* __restrict__ km_lo,
    const unsigned short* __restrict__ Urb,
    const float* __restrict__ q2p, const float* __restrict__ k2,
    const float* __restrict__ temp_p, const unsigned short* __restrict__ vT,
    unsigned short* __restrict__ ctxb)
{
    __shared__ __align__(16) unsigned short P_lds[4][32 * PROW];
    __shared__ __align__(16) float OP[4][32][64];
    __shared__ float ML[4][32];

    const int itile = blockIdx.x, bh = blockIdx.y;
    const int i0 = itile * 32;
    const int tid = threadIdx.x, w = tid >> 6, lane = tid & 63;
    const int l15 = lane & 15, quad = lane >> 4;

    const float inv_temp = 1.0f / fmaxf(temp_p[0], 0.5f);

    bf16x8 Ahi[2], Alo[2], Aur[4][2];
#pragma unroll
    for (int mi = 0; mi < 2; ++mi) {
        size_t ab = ((size_t)bh * T_ + i0 + mi * 16 + l15) * 32 + quad * 8;
        Ahi[mi] = *(const bf16x8*)&a_hi[ab];
        Alo[mi] = *(const bf16x8*)&a_lo[ab];
#pragma unroll
        for (int r = 0; r < 4; ++r)
            Aur[r][mi] = *(const bf16x8*)
                &Urb[(((size_t)bh * R_ + r) * T_ + i0 + mi * 16 + l15) * 32 + quad * 8];
    }
    float q2r[2][4];
#pragma unroll
    for (int mi = 0; mi < 2; ++mi)
#pragma unroll
        for (int rg = 0; rg < 4; ++rg)
            q2r[mi][rg] = q2p[(size_t)bh * T_ + i0 + mi * 16 + quad * 4 + rg];

    f32x4 Oacc[2][4] = {};
    float psum[2][4] = {};

    for (int jt = w; jt <= itile; jt += 4) {
        const int j0 = jt * 32;
        bf16x8 Bhi[2], Blo[2];
#pragma unroll
        for (int ni = 0; ni < 2; ++ni) {
            size_t kb = ((size_t)bh * T_ + j0 + ni * 16 + l15) * 32 + quad * 8;
            Bhi[ni] = *(const bf16x8*)&km_hi[kb];
            Blo[ni] = *(const bf16x8*)&km_lo[kb];
        }
        f32x4 acc[2][2] = {};
#pragma unroll
        for (int mi = 0; mi < 2; ++mi)
#pragma unroll
            for (int ni = 0; ni < 2; ++ni) {
                acc[mi][ni] = __builtin_amdgcn_mfma_f32_16x16x32_bf16(
                    Alo[mi], Bhi[ni], acc[mi][ni], 0, 0, 0);
                acc[mi][ni] = __builtin_amdgcn_mfma_f32_16x16x32_bf16(
                    Ahi[mi], Blo[ni], acc[mi][ni], 0, 0, 0);
                acc[mi][ni] = __builtin_amdgcn_mfma_f32_16x16x32_bf16(
                    Ahi[mi], Bhi[ni], acc[mi][ni], 0, 0, 0);
            }
        f32x4 sq[2][2] = {};
#pragma unroll
        for (int r = 0; r < 4; ++r) {
            f32x4 ar[2][2] = {};
#pragma unroll
            for (int mi = 0; mi < 2; ++mi)
#pragma unroll
                for (int ni = 0; ni < 2; ++ni)
                    ar[mi][ni] = __builtin_amdgcn_mfma_f32_16x16x32_bf16(
                        Aur[r][mi], Bhi[ni], ar[mi][ni], 0, 0, 0);
#pragma unroll
            for (int mi = 0; mi < 2; ++mi)
#pragma unroll
                for (int ni = 0; ni < 2; ++ni)
                    sq[mi][ni] += ar[mi][ni] * ar[mi][ni];
        }
        float k2c[2];
#pragma unroll
        for (int ni = 0; ni < 2; ++ni)
            k2c[ni] = k2[(size_t)bh * T_ + j0 + ni * 16 + l15];
        const bool diag = (jt == itile);
#pragma unroll
        for (int mi = 0; mi < 2; ++mi)
#pragma unroll
            for (int ni = 0; ni < 2; ++ni)
#pragma unroll
                for (int rg = 0; rg < 4; ++rg) {
                    float dist = q2r[mi][rg] + k2c[ni]
                               - 2.f * acc[mi][ni][rg] + sq[mi][ni][rg];
                    float sc = -fmaxf(dist, 0.f) * inv_temp;
                    if (diag && (ni * 16 + l15) > (mi * 16 + quad * 4 + rg))
                        sc = -1e30f;
                    float p = __expf(sc);      // scores <= 0: m=0 softmax exact
                    psum[mi][rg] += p;
                    P_lds[w][(mi * 16 + quad * 4 + rg) * PROW + ni * 16 + l15] = f2bf(p);
                }
        bf16x8 Pf[2], Vf[4];
#pragma unroll
        for (int mi = 0; mi < 2; ++mi)
            Pf[mi] = *(const bf16x8*)&P_lds[w][(mi * 16 + l15) * PROW + quad * 8];
#pragma unroll
        for (int n4 = 0; n4 < 4; ++n4)
            Vf[n4] = *(const bf16x8*)
                &vT[((size_t)bh * DH_ + n4 * 16 + l15) * T_ + j0 + quad * 8];
#pragma unroll
        for (int mi = 0; mi < 2; ++mi)
#pragma unroll
            for (int n4 = 0; n4 < 4; ++n4)
                Oacc[mi][n4] = __builtin_amdgcn_mfma_f32_16x16x32_bf16(
                    Pf[mi], Vf[n4], Oacc[mi][n4], 0, 0, 0);
    }

#pragma unroll
    for (int mi = 0; mi < 2; ++mi)
#pragma unroll
        for (int rg = 0; rg < 4; ++rg) {
            float v = psum[mi][rg];
            v += __shfl_xor(v, 1); v += __shfl_xor(v, 2);
            v += __shfl_xor(v, 4); v += __shfl_xor(v, 8);
            psum[mi][rg] = v;
        }
    if (l15 == 0)
#pragma unroll
        for (int mi = 0; mi < 2; ++mi)
#pragma unroll
            for (int rg = 0; rg < 4; ++rg)
                ML[w][mi * 16 + quad * 4 + rg] = psum[mi][rg];
#pragma unroll
    for (int mi = 0; mi < 2; ++mi)
#pragma unroll
        for (int n4 = 0; n4 < 4; ++n4)
#pragma unroll
            for (int rg = 0; rg < 4; ++rg)
                OP[w][mi * 16 + quad * 4 + rg][n4 * 16 + l15] = Oacc[mi][n4][rg];
    __syncthreads();

    const int ii = tid >> 3, ds = tid & 7;
    float l = ML[0][ii] + ML[1][ii] + ML[2][ii] + ML[3][ii];
    float O[8] = {};
#pragma unroll
    for (int wv = 0; wv < 4; ++wv) {
        float4 o0 = *(const float4*)&OP[wv][ii][ds * 8];
        float4 o1 = *(const float4*)&OP[wv][ii][ds * 8 + 4];
        O[0] += o0.x; O[1] += o0.y; O[2] += o0.z; O[3] += o0.w;
        O[4] += o1.x; O[5] += o1.y; O[6] += o1.z; O[7] += o1.w;
    }
    const float inv = 1.0f / l;
    const int b = bh >> 4, h = bh & 15;
    u16x8 o;
#pragma unroll
    for (int dd = 0; dd < 8; ++dd) o[dd] = f2bf(O[dd] * inv);
    *(u16x8*)&ctxb[((size_t)b * T_ + i0 + ii) * DM_ + h * 64 + ds * 8] = o;
}

// -------------------------------------------------------------------------
extern "C" void kernel_launch(void* const* d_in, const int* in_sizes, int n_in,
                              void* d_out, int out_size, void* d_ws, size_t ws_size,
                              hipStream_t stream)
{
    const float* x       = (const float*)d_in[0];
    const float* Wq      = (const float*)d_in[1];
    const float* Wk      = (const float*)d_in[2];
    const float* Wv      = (const float*)d_in[3];
    const float* Wo      = (const float*)d_in[4];
    const float* Wqm     = (const float*)d_in[5];
    const float* Wkm     = (const float*)d_in[6];
    const float* Wmetric = (const float*)d_in[7];
    const float* temp    = (const float*)d_in[8];
    float* out = (float*)d_out;
    float* ws  = (float*)d_ws;

    // fp32 region
    float* q_raw = ws;                                  // 1,048,576 f
    float* k_raw = q_raw + (size_t)BH_ * T_ * DH_;      // 1,048,576 f
    float* q2p   = k_raw + (size_t)BH_ * T_ * DH_;      //    16,384 f
    float* k2    = q2p   + (size_t)BH_ * T_;            //    16,384 f
    // u16 region
    unsigned short* xb   = (unsigned short*)(k2 + (size_t)BH_ * T_);
    unsigned short* wqb  = xb   + (size_t)DM_ * DM_;
    unsigned short* wkb  = wqb  + (size_t)DM_ * DM_;
    unsigned short* wvb  = wkb  + (size_t)DM_ * DM_;
    unsigned short* wob  = wvb  + (size_t)DM_ * DM_;
    unsigned short* a_hi = wob  + (size_t)DM_ * DM_;
    unsigned short* a_lo = a_hi + (size_t)BH_ * T_ * D_;
    unsigned short* kmhi = a_lo + (size_t)BH_ * T_ * D_;
    unsigned short* kmlo = kmhi + (size_t)BH_ * T_ * D_;
    unsigned short* Urb  = kmlo + (size_t)BH_ * T_ * D_;   // BH*R*T*D
    unsigned short* vT   = Urb  + (size_t)BH_ * R_ * T_ * D_;
    unsigned short* ctxb = (unsigned short*)q_raw;  // q_raw dead after feat
    // total ~ 30 MB (<< proven 59 MB)

    prep_kernel<<<dim3(16, 16, 5), 256, 0, stream>>>(
        x, Wq, Wk, Wv, Wo, xb, wqb, wkb, wvb, wob);
    mfma_gemm_db<0><<<dim3(48, 16), 256, 0, stream>>>(
        xb, wqb, wkb, wvb, q_raw, k_raw, vT);
    feat_both<<<dim3(BH_ * T_ / 4, 2), 256, 0, stream>>>(
        q_raw, k_raw, Wqm, Wkm, Wmetric,
        a_hi, a_lo, kmhi, kmlo, q2p, k2, Urb);
    attn_mfma<<<dim3(T_ / 32, BH_), 256, 0, stream>>>(
        a_hi, a_lo, kmhi, kmlo, Urb, q2p, k2, temp, vT, ctxb);
    mfma_gemm_db<1><<<dim3(16, 16), 256, 0, stream>>>(
        ctxb, wob, nullptr, nullptr, out, nullptr, nullptr);
}